// Round 1
// baseline (7409.408 us; speedup 1.0000x reference)
//
#include <hip/hip_runtime.h>
#include <math.h>

#define NN 128
#define SM 129   // padded LDS stride for 128-wide f32 tiles

// ---------------------------------------------------------------------------
// K1: build symmetric-normalized Laplacian per graph
// ---------------------------------------------------------------------------
__global__ void k1_laplacian(const int* __restrict__ src, const int* __restrict__ dst,
                             int E, float* __restrict__ Lout) {
  extern __shared__ float sm1[];            // A[128*129] + dinv[128]
  float* A    = sm1;
  float* dinv = sm1 + NN * SM;
  const int g   = blockIdx.x;
  const int tid = threadIdx.x;

  for (int e = tid; e < NN * NN; e += 256) {
    int i = e >> 7, j = e & 127;
    A[i * SM + j] = 0.f;
  }
  __syncthreads();
  const int* s = src + (size_t)g * E;
  const int* d = dst + (size_t)g * E;
  for (int e = tid; e < E; e += 256) {
    int a = s[e], b = d[e];
    A[a * SM + b] = 1.f;     // benign races: all write 1.0
    A[b * SM + a] = 1.f;
  }
  __syncthreads();
  if (tid < NN) {
    float acc = 0.f;
    for (int j = 0; j < NN; ++j) acc += A[tid * SM + j];
    dinv[tid] = (acc > 0.f) ? (float)(1.0 / sqrt((double)acc)) : 0.f;
  }
  __syncthreads();
  float* Lg = Lout + (size_t)g * NN * NN;
  for (int e = tid; e < NN * NN; e += 256) {
    int i = e >> 7, j = e & 127;
    Lg[e] = ((i == j) ? 1.f : 0.f) - dinv[i] * dinv[j] * A[i * SM + j];
  }
}

// ---------------------------------------------------------------------------
// K2: per (graph, filter): K = (L-bI)^4 + aI  ->  invert (fp64, in-register GJ)
//     -> atomically accumulate  W += sqrt(2)*a*Cn[f] * K^{-1}
// Thread map: 16x16; thread (tr,tc) owns rows 8tr+v (v=0..7), cols tc+16u (u=0..7)
// ---------------------------------------------------------------------------
__global__ void k2_filter(const float* __restrict__ L, const float* __restrict__ C,
                          int NF, float* __restrict__ W) {
  extern __shared__ float sm2[];            // 128*129 f32; aliased by GJ row/col (f64)
  double* ldsrow = (double*)sm2;            // 128 doubles
  double* ldscol = ((double*)sm2) + NN;     // 128 doubles
  const int bid = blockIdx.x;
  const int g = bid / NF;
  const int f = bid % NF;
  const int tid = threadIdx.x;
  const int tr = tid >> 4;                  // 0..15
  const int tc = tid & 15;                  // 0..15

  // filter coefficient (all threads redundantly, cached reads)
  double csum = 0.0;
  for (int q = 0; q < NF; ++q) { double c = (double)C[q]; csum += c * c; }
  double cn = sqrt(csum); if (cn < 1e-12) cn = 1e-12;
  const double a4 = 0.05 * 0.05 * 0.05 * 0.05;               // (STEP/2)^4
  const double coef = 1.4142135623730951 * a4 * ((double)C[f] / cn);
  const float  bf = (float)((double)f * 0.1);

  // phase 1: M = L - b I  into LDS
  const float* Lg = L + (size_t)g * NN * NN;
  for (int e = tid; e < NN * NN; e += 256) {
    int i = e >> 7, j = e & 127;
    float v = Lg[e];
    if (i == j) v -= bf;
    sm2[i * SM + j] = v;
  }
  __syncthreads();

  // phase 2: P2 = M @ M   (fp32 regs)
  float p2[8][8];
#pragma unroll
  for (int v = 0; v < 8; ++v)
#pragma unroll
    for (int u = 0; u < 8; ++u) p2[v][u] = 0.f;
  for (int k = 0; k < NN; ++k) {
    float av[8], bv[8];
#pragma unroll
    for (int v = 0; v < 8; ++v) av[v] = sm2[(8 * tr + v) * SM + k];
#pragma unroll
    for (int u = 0; u < 8; ++u) bv[u] = sm2[k * SM + tc + 16 * u];
#pragma unroll
    for (int v = 0; v < 8; ++v)
#pragma unroll
      for (int u = 0; u < 8; ++u) p2[v][u] = fmaf(av[v], bv[u], p2[v][u]);
  }
  __syncthreads();
  // phase 3: P2 -> LDS (overwrite M)
#pragma unroll
  for (int v = 0; v < 8; ++v)
#pragma unroll
    for (int u = 0; u < 8; ++u) sm2[(8 * tr + v) * SM + tc + 16 * u] = p2[v][u];
  __syncthreads();

  // phase 4: K = P2 @ P2 + a I   (fp64 regs)
  double kr[8][8];
#pragma unroll
  for (int v = 0; v < 8; ++v)
#pragma unroll
    for (int u = 0; u < 8; ++u)
      kr[v][u] = ((8 * tr + v) == (tc + 16 * u)) ? a4 : 0.0;
  for (int k = 0; k < NN; ++k) {
    double av[8], bv[8];
#pragma unroll
    for (int v = 0; v < 8; ++v) av[v] = (double)sm2[(8 * tr + v) * SM + k];
#pragma unroll
    for (int u = 0; u < 8; ++u) bv[u] = (double)sm2[k * SM + tc + 16 * u];
#pragma unroll
    for (int v = 0; v < 8; ++v)
#pragma unroll
      for (int u = 0; u < 8; ++u) kr[v][u] = fma(av[v], bv[u], kr[v][u]);
  }
  __syncthreads();   // P2 dead; ldsrow/ldscol alias its LDS

  // phase 5: in-place Gauss-Jordan inversion (SPD -> no pivoting needed)
  for (int k = 0; k < NN; ++k) {
    if (tr == (k >> 3)) {                    // row-k owners write raw row
#pragma unroll
      for (int v = 0; v < 8; ++v)
        if (v == (k & 7)) {
#pragma unroll
          for (int u = 0; u < 8; ++u) ldsrow[tc + 16 * u] = kr[v][u];
        }
    }
    if (tc == (k & 15)) {                    // col-k owners write current col
#pragma unroll
      for (int u = 0; u < 8; ++u)
        if (u == (k >> 4)) {
#pragma unroll
          for (int v = 0; v < 8; ++v) ldscol[8 * tr + v] = kr[v][u];
        }
    }
    __syncthreads();
    double dp = 1.0 / ldsrow[k];
#pragma unroll
    for (int v = 0; v < 8; ++v) {
      int i = 8 * tr + v;
      if (i == k) {
#pragma unroll
        for (int u = 0; u < 8; ++u) {
          int col = tc + 16 * u;
          kr[v][u] = (col == k) ? dp : kr[v][u] * dp;
        }
      } else {
        double fd = ldscol[i] * dp;
#pragma unroll
        for (int u = 0; u < 8; ++u) {
          int col = tc + 16 * u;
          kr[v][u] = (col == k) ? -fd : fma(-fd, ldsrow[col], kr[v][u]);
        }
      }
    }
    __syncthreads();
  }

  // phase 6: accumulate W
  float* Wg = W + (size_t)g * NN * NN;
#pragma unroll
  for (int v = 0; v < 8; ++v)
#pragma unroll
    for (int u = 0; u < 8; ++u)
      atomicAdd(&Wg[(8 * tr + v) * NN + tc + 16 * u], (float)(coef * kr[v][u]));
}

// ---------------------------------------------------------------------------
// K3a: Y = X - W @ X  per (graph, d-chunk of 128); also per-chunk emb (col means)
// Uses W symmetry: reads W by rows (conflict-free).
// ---------------------------------------------------------------------------
__global__ void k3a_y(const float* __restrict__ x, const float* __restrict__ rs,
                      const float* __restrict__ W, float* __restrict__ Y,
                      float* __restrict__ emb, int F0, int R, int DTOT, int NCH,
                      float rscale) {
  extern __shared__ float sm3[];
  float* ldsW = sm3;                 // 128*129
  float* ldsX = sm3 + NN * SM;       // 128*129
  const int bid = blockIdx.x;
  const int g = bid / NCH;
  const int c = bid % NCH;
  const int d0 = c * 128;
  const int tid = threadIdx.x, tr = tid >> 4, tc = tid & 15;

  const float* Wg = W + (size_t)g * NN * NN;
  for (int e = tid; e < NN * NN; e += 256) {
    int k = e >> 7, i = e & 127;
    ldsW[k * SM + i] = Wg[e];
  }
  const float* xg = x + (size_t)g * NN * F0;
  const float* rg = rs + (size_t)g * NN * R;
  for (int e = tid; e < NN * NN; e += 256) {
    int k = e >> 7, dl = e & 127;
    int d = d0 + dl;
    float v = 0.f;
    if (d < DTOT) v = (d < F0) ? xg[k * F0 + d] : rg[k * R + (d - F0)] * rscale;
    ldsX[k * SM + dl] = v;
  }
  __syncthreads();

  float acc[8][8];
#pragma unroll
  for (int v = 0; v < 8; ++v)
#pragma unroll
    for (int u = 0; u < 8; ++u) acc[v][u] = 0.f;
  for (int k = 0; k < NN; ++k) {
    float wv[8], xv[8];
#pragma unroll
    for (int v = 0; v < 8; ++v) wv[v] = ldsW[k * SM + 8 * tr + v];  // W[k][i] == W[i][k]
#pragma unroll
    for (int u = 0; u < 8; ++u) xv[u] = ldsX[k * SM + tc + 16 * u];
#pragma unroll
    for (int v = 0; v < 8; ++v)
#pragma unroll
      for (int u = 0; u < 8; ++u) acc[v][u] = fmaf(wv[v], xv[u], acc[v][u]);
  }
  // y = x - acc ; write Y; keep y in acc for emb partials
  float* Yg = Y + (size_t)g * NN * 1152;
#pragma unroll
  for (int v = 0; v < 8; ++v)
#pragma unroll
    for (int u = 0; u < 8; ++u) {
      float yv = ldsX[(8 * tr + v) * SM + tc + 16 * u] - acc[v][u];
      acc[v][u] = yv;
      Yg[(8 * tr + v) * 1152 + d0 + tc + 16 * u] = yv;
    }
  __syncthreads();                    // ldsW dead -> reuse as emb partial buffer
  float* embp = ldsW;                 // [16][128]
#pragma unroll
  for (int u = 0; u < 8; ++u) {
    float s = 0.f;
#pragma unroll
    for (int v = 0; v < 8; ++v) s += acc[v][u];
    embp[tr * 128 + tc + 16 * u] = s;
  }
  __syncthreads();
  if (tid < 128) {
    int d = d0 + tid;
    if (d < DTOT) {
      float s = 0.f;
      for (int t = 0; t < 16; ++t) s += embp[t * 128 + tid];
      emb[(size_t)g * 1152 + d] = s * (1.f / 128.f);
    }
  }
}

// ---------------------------------------------------------------------------
// K3b: G += Ychunk @ Ychunk^T  per (graph, d-chunk), via transposed LDS tile
// ---------------------------------------------------------------------------
__global__ void k3b_gram(const float* __restrict__ Y, float* __restrict__ G,
                         int DTOT, int NCH) {
  extern __shared__ float sm4[];     // Yt[128 d][132]
  const int ST = 132;
  const int bid = blockIdx.x;
  const int g = bid / NCH, c = bid % NCH, d0 = c * 128;
  const int tid = threadIdx.x, tr = tid >> 4, tc = tid & 15;
  const float* Yg = Y + (size_t)g * NN * 1152;
  for (int e = tid; e < NN * NN; e += 256) {
    int i = e >> 7, dl = e & 127;
    int d = d0 + dl;
    sm4[dl * ST + i] = (d < DTOT) ? Yg[i * 1152 + d] : 0.f;
  }
  __syncthreads();
  float gg[8][8];
#pragma unroll
  for (int v = 0; v < 8; ++v)
#pragma unroll
    for (int u = 0; u < 8; ++u) gg[v][u] = 0.f;
  for (int dl = 0; dl < 128; ++dl) {
    float av[8], bv[8];
#pragma unroll
    for (int v = 0; v < 8; ++v) av[v] = sm4[dl * ST + 8 * tr + v];
#pragma unroll
    for (int u = 0; u < 8; ++u) bv[u] = sm4[dl * ST + tc + 16 * u];
#pragma unroll
    for (int v = 0; v < 8; ++v)
#pragma unroll
      for (int u = 0; u < 8; ++u) gg[v][u] = fmaf(av[v], bv[u], gg[v][u]);
  }
  float* Gg = G + (size_t)g * NN * NN;
#pragma unroll
  for (int v = 0; v < 8; ++v)
#pragma unroll
    for (int u = 0; u < 8; ++u)
      atomicAdd(&Gg[(8 * tr + v) * NN + tc + 16 * u], gg[v][u]);
}

// ---------------------------------------------------------------------------
// K4: sp_g = -sum_ij |G_ij| / (n_i n_j) / N^2 ,  n_i = max(sqrt(G_ii), 1e-12)
// ---------------------------------------------------------------------------
__global__ void k4_sp(const float* __restrict__ G, double* __restrict__ spt) {
  __shared__ float inr[NN];
  __shared__ double red[4];
  const int g = blockIdx.x, tid = threadIdx.x;
  const float* Gg = G + (size_t)g * NN * NN;
  if (tid < NN) {
    float n = sqrtf(fmaxf(Gg[tid * NN + tid], 0.f));
    inr[tid] = 1.f / fmaxf(n, 1e-12f);
  }
  __syncthreads();
  double s = 0.0;
  for (int e = tid; e < NN * NN; e += 256) {
    int i = e >> 7, j = e & 127;
    s += (double)(fabsf(Gg[e]) * inr[i] * inr[j]);
  }
  for (int off = 32; off; off >>= 1) s += __shfl_down(s, off);
  int wave = tid >> 6, lane = tid & 63;
  if (lane == 0) red[wave] = s;
  __syncthreads();
  if (tid == 0) spt[g] = -(red[0] + red[1] + red[2] + red[3]) / (double)(NN * NN);
}

// ---------------------------------------------------------------------------
// K5a: 64x64 pairwise-distance matrix over embeddings
// ---------------------------------------------------------------------------
__global__ void k5a_cdist(const float* __restrict__ emb, float* __restrict__ Dm,
                          int DTOT) {
  __shared__ float red[4];
  const int i = blockIdx.x, tid = threadIdx.x;
  float ei[5];
#pragma unroll
  for (int s2 = 0; s2 < 5; ++s2) {
    int d = tid + 256 * s2;
    ei[s2] = (d < DTOT) ? emb[(size_t)i * 1152 + d] : 0.f;
  }
  for (int j = 0; j < 64; ++j) {
    float acc = 0.f;
#pragma unroll
    for (int s2 = 0; s2 < 5; ++s2) {
      int d = tid + 256 * s2;
      if (d < DTOT) {
        float df = ei[s2] - emb[(size_t)j * 1152 + d];
        acc = fmaf(df, df, acc);
      }
    }
    for (int off = 32; off; off >>= 1) acc += __shfl_down(acc, off);
    int wave = tid >> 6, lane = tid & 63;
    if (lane == 0) red[wave] = acc;
    __syncthreads();
    if (tid == 0) {
      float d2 = red[0] + red[1] + red[2] + red[3];
      Dm[i * 64 + j] = (d2 > 0.f) ? sqrtf(d2) : 0.f;
    }
    __syncthreads();
  }
}

// ---------------------------------------------------------------------------
// K5b: final scalar (single wave)
// ---------------------------------------------------------------------------
__global__ void k5b_final(const float* __restrict__ Dm, const double* __restrict__ spt,
                          const float* __restrict__ C, int NF,
                          const int* __restrict__ ncls, float* __restrict__ out) {
  const int lane = threadIdx.x;    // 64 threads = 1 wave
  const int nc = ncls[0];
  // sparsity_fwd = sum_i sp_i * B^{-(B-i)}
  double spf = spt[lane] * exp(-((double)(64 - lane)) * log(64.0));
  for (int off = 32; off; off >>= 1) spf += __shfl_down(spf, off);

  double hl1 = 0.0, hl2 = 0.0;
  const double beta = 1.0 / (double)nc + 1e-13;
  for (int cc = 0; cc < nc; ++cc) {
    bool ip = (lane % nc) == cc;
    double ps = 0.0, ns = 0.0;
    for (int j = 0; j < 64; ++j) {
      double dv = (double)Dm[lane * 64 + j];
      bool jp = (j % nc) == cc;
      if (ip && jp) ps += dv;
      if (!ip && !jp) ns += dv;
    }
    for (int off = 32; off; off >>= 1) {
      ps += __shfl_down(ps, off);
      ns += __shfl_down(ns, off);
    }
    int npos = 0;
    for (int q = 0; q < 64; ++q) if (q % nc == cc) npos++;
    int nneg = 64 - npos;
    hl2 += ps / ((double)npos * (double)npos);
    hl1 += -(ns / ((double)nneg * (double)nneg)) / beta;
  }
  if (lane == 0) {
    double l1 = 0.0, l2 = 0.0;
    for (int q = 0; q < NF; ++q) { double cv = (double)C[q]; l1 += fabs(cv); l2 += cv * cv; }
    l2 = sqrt(l2); if (l2 < 1e-12) l2 = 1e-12;
    double dims = sqrt((double)NF);
    double sc = (dims - l1 / l2) / (dims - 1.0);
    out[0] = (float)(sc + hl2 + hl1 + spf);
  }
}

// ---------------------------------------------------------------------------
extern "C" void kernel_launch(void* const* d_in, const int* in_sizes, int n_in,
                              void* d_out, int out_size, void* d_ws, size_t ws_size,
                              hipStream_t stream) {
  (void)n_in; (void)out_size; (void)ws_size;
  const float* x    = (const float*)d_in[0];
  const float* rs   = (const float*)d_in[1];
  const float* C    = (const float*)d_in[2];
  const int*   esrc = (const int*)d_in[3];
  const int*   edst = (const int*)d_in[4];
  const int*   ncls = (const int*)d_in[5];
  float* out = (float*)d_out;

  const int F0   = in_sizes[0] / (64 * 128);
  const int R    = in_sizes[1] / (64 * 128);
  const int NF   = in_sizes[2];
  const int E    = in_sizes[3] / 64;
  const int DTOT = F0 + R;
  const int NCH  = (DTOT + 127) / 128;
  const float rscale = (float)(1.0 / sqrt((double)R));

  char* ws = (char*)d_ws;
  size_t off = 0;
  float*  L   = (float*)(ws + off);  off += (size_t)64 * NN * NN * 4;     // 4 MiB
  float*  W   = (float*)(ws + off);  off += (size_t)64 * NN * NN * 4;     // 4 MiB
  float*  Y   = (float*)(ws + off);  off += (size_t)64 * NN * 1152 * 4;   // 36 MiB
  float*  G   = (float*)(ws + off);  off += (size_t)64 * NN * NN * 4;     // 4 MiB
  float*  emb = (float*)(ws + off);  off += (size_t)64 * 1152 * 4;
  double* spt = (double*)(ws + off); off += (size_t)64 * 8;
  float*  Dm  = (float*)(ws + off);  off += (size_t)64 * 64 * 4;

  hipMemsetAsync(W, 0, (size_t)64 * NN * NN * 4, stream);
  hipMemsetAsync(G, 0, (size_t)64 * NN * NN * 4, stream);

  const int lds1  = (NN * SM + NN) * 4;     // 66560
  const int lds2  = (NN * SM) * 4;          // 66048
  const int lds3a = (NN * SM) * 4 * 2;      // 132096
  const int lds3b = NN * 132 * 4;           // 67584
  hipFuncSetAttribute((const void*)k1_laplacian, hipFuncAttributeMaxDynamicSharedMemorySize, lds1);
  hipFuncSetAttribute((const void*)k2_filter,    hipFuncAttributeMaxDynamicSharedMemorySize, lds2);
  hipFuncSetAttribute((const void*)k3a_y,        hipFuncAttributeMaxDynamicSharedMemorySize, lds3a);
  hipFuncSetAttribute((const void*)k3b_gram,     hipFuncAttributeMaxDynamicSharedMemorySize, lds3b);

  k1_laplacian<<<64, 256, lds1, stream>>>(esrc, edst, E, L);
  k2_filter<<<64 * NF, 256, lds2, stream>>>(L, C, NF, W);
  k3a_y<<<64 * NCH, 256, lds3a, stream>>>(x, rs, W, Y, emb, F0, R, DTOT, NCH, rscale);
  k3b_gram<<<64 * NCH, 256, lds3b, stream>>>(Y, G, DTOT, NCH);
  k4_sp<<<64, 256, 0, stream>>>(G, spt);
  k5a_cdist<<<64, 256, 0, stream>>>(emb, Dm, DTOT);
  k5b_final<<<1, 64, 0, stream>>>(Dm, spt, C, NF, ncls, out);
}

// Round 2
// 2180.084 us; speedup vs baseline: 3.3987x; 3.3987x over previous
//
#include <hip/hip_runtime.h>
#include <math.h>

#define NN 128
#define SM 129   // padded LDS stride for 128-wide f32 tiles

// ---------------------------------------------------------------------------
// K1: build symmetric-normalized Laplacian per graph
// ---------------------------------------------------------------------------
__global__ __launch_bounds__(256) void k1_laplacian(
    const int* __restrict__ src, const int* __restrict__ dst,
    int E, float* __restrict__ Lout) {
  extern __shared__ float sm1[];            // A[128*129] + dinv[128]
  float* A    = sm1;
  float* dinv = sm1 + NN * SM;
  const int g   = blockIdx.x;
  const int tid = threadIdx.x;

  for (int e = tid; e < NN * NN; e += 256) {
    int i = e >> 7, j = e & 127;
    A[i * SM + j] = 0.f;
  }
  __syncthreads();
  const int* s = src + (size_t)g * E;
  const int* d = dst + (size_t)g * E;
  for (int e = tid; e < E; e += 256) {
    int a = s[e], b = d[e];
    A[a * SM + b] = 1.f;     // benign races: all write 1.0
    A[b * SM + a] = 1.f;
  }
  __syncthreads();
  if (tid < NN) {
    float acc = 0.f;
    for (int j = 0; j < NN; ++j) acc += A[tid * SM + j];
    dinv[tid] = (acc > 0.f) ? (float)(1.0 / sqrt((double)acc)) : 0.f;
  }
  __syncthreads();
  float* Lg = Lout + (size_t)g * NN * NN;
  for (int e = tid; e < NN * NN; e += 256) {
    int i = e >> 7, j = e & 127;
    Lg[e] = ((i == j) ? 1.f : 0.f) - dinv[i] * dinv[j] * A[i * SM + j];
  }
}

// ---------------------------------------------------------------------------
// K2: per (graph, filter): K = (L-bI)^4 + aI  ->  invert (fp64, in-register GJ)
//     -> atomically accumulate  W += sqrt(2)*a*Cn[f] * K^{-1}
// Thread map: 16x16; thread (tr,tc) owns rows 8tr+v (v=0..7), cols tc+16u (u=0..7)
// __launch_bounds__(256,1): kr[8][8] f64 = 128 VGPRs; default bounds capped
// allocation at 64 VGPR -> full spill -> 14 GB scratch traffic (R1 rocprof).
// ---------------------------------------------------------------------------
__global__ __launch_bounds__(256, 1) void k2_filter(
    const float* __restrict__ L, const float* __restrict__ C,
    int NF, float* __restrict__ W) {
  extern __shared__ float sm2[];            // 128*129 f32; aliased by GJ row/col (f64)
  double* ldsrow = (double*)sm2;            // 128 doubles
  double* ldscol = ((double*)sm2) + NN;     // 128 doubles
  const int bid = blockIdx.x;
  const int g = bid / NF;
  const int f = bid % NF;
  const int tid = threadIdx.x;
  const int tr = tid >> 4;                  // 0..15
  const int tc = tid & 15;                  // 0..15

  // filter coefficient (all threads redundantly, cached reads)
  double csum = 0.0;
  for (int q = 0; q < NF; ++q) { double c = (double)C[q]; csum += c * c; }
  double cn = sqrt(csum); if (cn < 1e-12) cn = 1e-12;
  const double a4 = 0.05 * 0.05 * 0.05 * 0.05;               // (STEP/2)^4
  const double coef = 1.4142135623730951 * a4 * ((double)C[f] / cn);
  const float  bf = (float)((double)f * 0.1);

  // phase 1: M = L - b I  into LDS
  const float* Lg = L + (size_t)g * NN * NN;
  for (int e = tid; e < NN * NN; e += 256) {
    int i = e >> 7, j = e & 127;
    float v = Lg[e];
    if (i == j) v -= bf;
    sm2[i * SM + j] = v;
  }
  __syncthreads();

  // phase 2: P2 = M @ M   (fp32 regs)
  float p2[8][8];
#pragma unroll
  for (int v = 0; v < 8; ++v)
#pragma unroll
    for (int u = 0; u < 8; ++u) p2[v][u] = 0.f;
  for (int k = 0; k < NN; ++k) {
    float av[8], bv[8];
#pragma unroll
    for (int v = 0; v < 8; ++v) av[v] = sm2[(8 * tr + v) * SM + k];
#pragma unroll
    for (int u = 0; u < 8; ++u) bv[u] = sm2[k * SM + tc + 16 * u];
#pragma unroll
    for (int v = 0; v < 8; ++v)
#pragma unroll
      for (int u = 0; u < 8; ++u) p2[v][u] = fmaf(av[v], bv[u], p2[v][u]);
  }
  __syncthreads();
  // phase 3: P2 -> LDS (overwrite M)
#pragma unroll
  for (int v = 0; v < 8; ++v)
#pragma unroll
    for (int u = 0; u < 8; ++u) sm2[(8 * tr + v) * SM + tc + 16 * u] = p2[v][u];
  __syncthreads();

  // phase 4: K = P2 @ P2 + a I   (fp64 regs)
  double kr[8][8];
#pragma unroll
  for (int v = 0; v < 8; ++v)
#pragma unroll
    for (int u = 0; u < 8; ++u)
      kr[v][u] = ((8 * tr + v) == (tc + 16 * u)) ? a4 : 0.0;
  for (int k = 0; k < NN; ++k) {
    double av[8], bv[8];
#pragma unroll
    for (int v = 0; v < 8; ++v) av[v] = (double)sm2[(8 * tr + v) * SM + k];
#pragma unroll
    for (int u = 0; u < 8; ++u) bv[u] = (double)sm2[k * SM + tc + 16 * u];
#pragma unroll
    for (int v = 0; v < 8; ++v)
#pragma unroll
      for (int u = 0; u < 8; ++u) kr[v][u] = fma(av[v], bv[u], kr[v][u]);
  }
  __syncthreads();   // P2 dead; ldsrow/ldscol alias its LDS

  // phase 5: in-place Gauss-Jordan inversion (SPD -> no pivoting needed)
  for (int k = 0; k < NN; ++k) {
    if (tr == (k >> 3)) {                    // row-k owners write raw row
#pragma unroll
      for (int v = 0; v < 8; ++v)
        if (v == (k & 7)) {
#pragma unroll
          for (int u = 0; u < 8; ++u) ldsrow[tc + 16 * u] = kr[v][u];
        }
    }
    if (tc == (k & 15)) {                    // col-k owners write current col
#pragma unroll
      for (int u = 0; u < 8; ++u)
        if (u == (k >> 4)) {
#pragma unroll
          for (int v = 0; v < 8; ++v) ldscol[8 * tr + v] = kr[v][u];
        }
    }
    __syncthreads();
    double dp = 1.0 / ldsrow[k];
#pragma unroll
    for (int v = 0; v < 8; ++v) {
      int i = 8 * tr + v;
      if (i == k) {
#pragma unroll
        for (int u = 0; u < 8; ++u) {
          int col = tc + 16 * u;
          kr[v][u] = (col == k) ? dp : kr[v][u] * dp;
        }
      } else {
        double fd = ldscol[i] * dp;
#pragma unroll
        for (int u = 0; u < 8; ++u) {
          int col = tc + 16 * u;
          kr[v][u] = (col == k) ? -fd : fma(-fd, ldsrow[col], kr[v][u]);
        }
      }
    }
    __syncthreads();
  }

  // phase 6: accumulate W
  float* Wg = W + (size_t)g * NN * NN;
#pragma unroll
  for (int v = 0; v < 8; ++v)
#pragma unroll
    for (int u = 0; u < 8; ++u)
      atomicAdd(&Wg[(8 * tr + v) * NN + tc + 16 * u], (float)(coef * kr[v][u]));
}

// ---------------------------------------------------------------------------
// K3a: Y = X - W @ X  per (graph, d-chunk of 128); also per-chunk emb (col means)
// Uses W symmetry: reads W by rows (conflict-free).
// ---------------------------------------------------------------------------
__global__ __launch_bounds__(256, 2) void k3a_y(
    const float* __restrict__ x, const float* __restrict__ rs,
    const float* __restrict__ W, float* __restrict__ Y,
    float* __restrict__ emb, int F0, int R, int DTOT, int NCH,
    float rscale) {
  extern __shared__ float sm3[];
  float* ldsW = sm3;                 // 128*129
  float* ldsX = sm3 + NN * SM;       // 128*129
  const int bid = blockIdx.x;
  const int g = bid / NCH;
  const int c = bid % NCH;
  const int d0 = c * 128;
  const int tid = threadIdx.x, tr = tid >> 4, tc = tid & 15;

  const float* Wg = W + (size_t)g * NN * NN;
  for (int e = tid; e < NN * NN; e += 256) {
    int k = e >> 7, i = e & 127;
    ldsW[k * SM + i] = Wg[e];
  }
  const float* xg = x + (size_t)g * NN * F0;
  const float* rg = rs + (size_t)g * NN * R;
  for (int e = tid; e < NN * NN; e += 256) {
    int k = e >> 7, dl = e & 127;
    int d = d0 + dl;
    float v = 0.f;
    if (d < DTOT) v = (d < F0) ? xg[k * F0 + d] : rg[k * R + (d - F0)] * rscale;
    ldsX[k * SM + dl] = v;
  }
  __syncthreads();

  float acc[8][8];
#pragma unroll
  for (int v = 0; v < 8; ++v)
#pragma unroll
    for (int u = 0; u < 8; ++u) acc[v][u] = 0.f;
  for (int k = 0; k < NN; ++k) {
    float wv[8], xv[8];
#pragma unroll
    for (int v = 0; v < 8; ++v) wv[v] = ldsW[k * SM + 8 * tr + v];  // W[k][i] == W[i][k]
#pragma unroll
    for (int u = 0; u < 8; ++u) xv[u] = ldsX[k * SM + tc + 16 * u];
#pragma unroll
    for (int v = 0; v < 8; ++v)
#pragma unroll
      for (int u = 0; u < 8; ++u) acc[v][u] = fmaf(wv[v], xv[u], acc[v][u]);
  }
  // y = x - acc ; write Y; keep y in acc for emb partials
  float* Yg = Y + (size_t)g * NN * 1152;
#pragma unroll
  for (int v = 0; v < 8; ++v)
#pragma unroll
    for (int u = 0; u < 8; ++u) {
      float yv = ldsX[(8 * tr + v) * SM + tc + 16 * u] - acc[v][u];
      acc[v][u] = yv;
      Yg[(8 * tr + v) * 1152 + d0 + tc + 16 * u] = yv;
    }
  __syncthreads();                    // ldsW dead -> reuse as emb partial buffer
  float* embp = ldsW;                 // [16][128]
#pragma unroll
  for (int u = 0; u < 8; ++u) {
    float s = 0.f;
#pragma unroll
    for (int v = 0; v < 8; ++v) s += acc[v][u];
    embp[tr * 128 + tc + 16 * u] = s;
  }
  __syncthreads();
  if (tid < 128) {
    int d = d0 + tid;
    if (d < DTOT) {
      float s = 0.f;
      for (int t = 0; t < 16; ++t) s += embp[t * 128 + tid];
      emb[(size_t)g * 1152 + d] = s * (1.f / 128.f);
    }
  }
}

// ---------------------------------------------------------------------------
// K3b: G += Ychunk @ Ychunk^T  per (graph, d-chunk), via transposed LDS tile
// ---------------------------------------------------------------------------
__global__ __launch_bounds__(256, 2) void k3b_gram(
    const float* __restrict__ Y, float* __restrict__ G,
    int DTOT, int NCH) {
  extern __shared__ float sm4[];     // Yt[128 d][132]
  const int ST = 132;
  const int bid = blockIdx.x;
  const int g = bid / NCH, c = bid % NCH, d0 = c * 128;
  const int tid = threadIdx.x, tr = tid >> 4, tc = tid & 15;
  const float* Yg = Y + (size_t)g * NN * 1152;
  for (int e = tid; e < NN * NN; e += 256) {
    int i = e >> 7, dl = e & 127;
    int d = d0 + dl;
    sm4[dl * ST + i] = (d < DTOT) ? Yg[i * 1152 + d] : 0.f;
  }
  __syncthreads();
  float gg[8][8];
#pragma unroll
  for (int v = 0; v < 8; ++v)
#pragma unroll
    for (int u = 0; u < 8; ++u) gg[v][u] = 0.f;
  for (int dl = 0; dl < 128; ++dl) {
    float av[8], bv[8];
#pragma unroll
    for (int v = 0; v < 8; ++v) av[v] = sm4[dl * ST + 8 * tr + v];
#pragma unroll
    for (int u = 0; u < 8; ++u) bv[u] = sm4[dl * ST + tc + 16 * u];
#pragma unroll
    for (int v = 0; v < 8; ++v)
#pragma unroll
      for (int u = 0; u < 8; ++u) gg[v][u] = fmaf(av[v], bv[u], gg[v][u]);
  }
  float* Gg = G + (size_t)g * NN * NN;
#pragma unroll
  for (int v = 0; v < 8; ++v)
#pragma unroll
    for (int u = 0; u < 8; ++u)
      atomicAdd(&Gg[(8 * tr + v) * NN + tc + 16 * u], gg[v][u]);
}

// ---------------------------------------------------------------------------
// K4: sp_g = -sum_ij |G_ij| / (n_i n_j) / N^2 ,  n_i = max(sqrt(G_ii), 1e-12)
// ---------------------------------------------------------------------------
__global__ __launch_bounds__(256) void k4_sp(const float* __restrict__ G,
                                             double* __restrict__ spt) {
  __shared__ float inr[NN];
  __shared__ double red[4];
  const int g = blockIdx.x, tid = threadIdx.x;
  const float* Gg = G + (size_t)g * NN * NN;
  if (tid < NN) {
    float n = sqrtf(fmaxf(Gg[tid * NN + tid], 0.f));
    inr[tid] = 1.f / fmaxf(n, 1e-12f);
  }
  __syncthreads();
  double s = 0.0;
  for (int e = tid; e < NN * NN; e += 256) {
    int i = e >> 7, j = e & 127;
    s += (double)(fabsf(Gg[e]) * inr[i] * inr[j]);
  }
  for (int off = 32; off; off >>= 1) s += __shfl_down(s, off);
  int wave = tid >> 6, lane = tid & 63;
  if (lane == 0) red[wave] = s;
  __syncthreads();
  if (tid == 0) spt[g] = -(red[0] + red[1] + red[2] + red[3]) / (double)(NN * NN);
}

// ---------------------------------------------------------------------------
// K5a: 64x64 pairwise-distance matrix over embeddings
// ---------------------------------------------------------------------------
__global__ __launch_bounds__(256) void k5a_cdist(const float* __restrict__ emb,
                                                 float* __restrict__ Dm, int DTOT) {
  __shared__ float red[4];
  const int i = blockIdx.x, tid = threadIdx.x;
  float ei[5];
#pragma unroll
  for (int s2 = 0; s2 < 5; ++s2) {
    int d = tid + 256 * s2;
    ei[s2] = (d < DTOT) ? emb[(size_t)i * 1152 + d] : 0.f;
  }
  for (int j = 0; j < 64; ++j) {
    float acc = 0.f;
#pragma unroll
    for (int s2 = 0; s2 < 5; ++s2) {
      int d = tid + 256 * s2;
      if (d < DTOT) {
        float df = ei[s2] - emb[(size_t)j * 1152 + d];
        acc = fmaf(df, df, acc);
      }
    }
    for (int off = 32; off; off >>= 1) acc += __shfl_down(acc, off);
    int wave = tid >> 6, lane = tid & 63;
    if (lane == 0) red[wave] = acc;
    __syncthreads();
    if (tid == 0) {
      float d2 = red[0] + red[1] + red[2] + red[3];
      Dm[i * 64 + j] = (d2 > 0.f) ? sqrtf(d2) : 0.f;
    }
    __syncthreads();
  }
}

// ---------------------------------------------------------------------------
// K5b: final scalar (single wave)
// ---------------------------------------------------------------------------
__global__ __launch_bounds__(64) void k5b_final(
    const float* __restrict__ Dm, const double* __restrict__ spt,
    const float* __restrict__ C, int NF,
    const int* __restrict__ ncls, float* __restrict__ out) {
  const int lane = threadIdx.x;    // 64 threads = 1 wave
  const int nc = ncls[0];
  // sparsity_fwd = sum_i sp_i * B^{-(B-i)}
  double spf = spt[lane] * exp(-((double)(64 - lane)) * log(64.0));
  for (int off = 32; off; off >>= 1) spf += __shfl_down(spf, off);

  double hl1 = 0.0, hl2 = 0.0;
  const double beta = 1.0 / (double)nc + 1e-13;
  for (int cc = 0; cc < nc; ++cc) {
    bool ip = (lane % nc) == cc;
    double ps = 0.0, ns = 0.0;
    for (int j = 0; j < 64; ++j) {
      double dv = (double)Dm[lane * 64 + j];
      bool jp = (j % nc) == cc;
      if (ip && jp) ps += dv;
      if (!ip && !jp) ns += dv;
    }
    for (int off = 32; off; off >>= 1) {
      ps += __shfl_down(ps, off);
      ns += __shfl_down(ns, off);
    }
    int npos = 0;
    for (int q = 0; q < 64; ++q) if (q % nc == cc) npos++;
    int nneg = 64 - npos;
    hl2 += ps / ((double)npos * (double)npos);
    hl1 += -(ns / ((double)nneg * (double)nneg)) / beta;
  }
  if (lane == 0) {
    double l1 = 0.0, l2 = 0.0;
    for (int q = 0; q < NF; ++q) { double cv = (double)C[q]; l1 += fabs(cv); l2 += cv * cv; }
    l2 = sqrt(l2); if (l2 < 1e-12) l2 = 1e-12;
    double dims = sqrt((double)NF);
    double sc = (dims - l1 / l2) / (dims - 1.0);
    out[0] = (float)(sc + hl2 + hl1 + spf);
  }
}

// ---------------------------------------------------------------------------
extern "C" void kernel_launch(void* const* d_in, const int* in_sizes, int n_in,
                              void* d_out, int out_size, void* d_ws, size_t ws_size,
                              hipStream_t stream) {
  (void)n_in; (void)out_size; (void)ws_size;
  const float* x    = (const float*)d_in[0];
  const float* rs   = (const float*)d_in[1];
  const float* C    = (const float*)d_in[2];
  const int*   esrc = (const int*)d_in[3];
  const int*   edst = (const int*)d_in[4];
  const int*   ncls = (const int*)d_in[5];
  float* out = (float*)d_out;

  const int F0   = in_sizes[0] / (64 * 128);
  const int R    = in_sizes[1] / (64 * 128);
  const int NF   = in_sizes[2];
  const int E    = in_sizes[3] / 64;
  const int DTOT = F0 + R;
  const int NCH  = (DTOT + 127) / 128;
  const float rscale = (float)(1.0 / sqrt((double)R));

  char* ws = (char*)d_ws;
  size_t off = 0;
  float*  L   = (float*)(ws + off);  off += (size_t)64 * NN * NN * 4;     // 4 MiB
  float*  W   = (float*)(ws + off);  off += (size_t)64 * NN * NN * 4;     // 4 MiB
  float*  Y   = (float*)(ws + off);  off += (size_t)64 * NN * 1152 * 4;   // 36 MiB
  float*  G   = (float*)(ws + off);  off += (size_t)64 * NN * NN * 4;     // 4 MiB
  float*  emb = (float*)(ws + off);  off += (size_t)64 * 1152 * 4;
  double* spt = (double*)(ws + off); off += (size_t)64 * 8;
  float*  Dm  = (float*)(ws + off);  off += (size_t)64 * 64 * 4;

  hipMemsetAsync(W, 0, (size_t)64 * NN * NN * 4, stream);
  hipMemsetAsync(G, 0, (size_t)64 * NN * NN * 4, stream);

  const int lds1  = (NN * SM + NN) * 4;     // 66560
  const int lds2  = (NN * SM) * 4;          // 66048
  const int lds3a = (NN * SM) * 4 * 2;      // 132096
  const int lds3b = NN * 132 * 4;           // 67584
  hipFuncSetAttribute((const void*)k1_laplacian, hipFuncAttributeMaxDynamicSharedMemorySize, lds1);
  hipFuncSetAttribute((const void*)k2_filter,    hipFuncAttributeMaxDynamicSharedMemorySize, lds2);
  hipFuncSetAttribute((const void*)k3a_y,        hipFuncAttributeMaxDynamicSharedMemorySize, lds3a);
  hipFuncSetAttribute((const void*)k3b_gram,     hipFuncAttributeMaxDynamicSharedMemorySize, lds3b);

  k1_laplacian<<<64, 256, lds1, stream>>>(esrc, edst, E, L);
  k2_filter<<<64 * NF, 256, lds2, stream>>>(L, C, NF, W);
  k3a_y<<<64 * NCH, 256, lds3a, stream>>>(x, rs, W, Y, emb, F0, R, DTOT, NCH, rscale);
  k3b_gram<<<64 * NCH, 256, lds3b, stream>>>(Y, G, DTOT, NCH);
  k4_sp<<<64, 256, 0, stream>>>(G, spt);
  k5a_cdist<<<64, 256, 0, stream>>>(emb, Dm, DTOT);
  k5b_final<<<1, 64, 0, stream>>>(Dm, spt, C, NF, ncls, out);
}